// Round 6
// baseline (245.286 us; speedup 1.0000x reference)
//
#include <hip/hip_runtime.h>

// Round 6: pair-per-chain f-split with DPP exchange; single fused kernel.
//
// Round-5 diagnosis: scheme was LDS-instruction-throughput-bound
// (128 DS instr/site/CU x ~6.1 cyc = 780 cyc/site measured), plus 68 us of
// second-kernel/graph overhead.
// This round: 2 lanes per (batch,side) chain. Lane f in {0,1} owns phi_f:
//   a_f[i] = sum_j v[j] * W[.][f][.]   (64 fma from a contiguous 64-float
//            LDS slice staged as [site][f][d][e]; 16 ds_read_b128,
//            pair lanes read the same address -> 2-way broadcast, free)
//   v[i]   = s_f*a_f[i] + dpp_swap(s_f*a_f[i])   (s_0=1-p, s_1=p)
// The cross-lane exchange is v_mov_dpp quad_perm(1,0,3,2) -- VALU pipe,
// ZERO DS instructions. Both lanes end with identical full v (a+b == b+a).
// DS per chain-site: 0.53 vs round-5's 1.0; waves: 1024 (1/SIMD).
// Staging: global->regs BEFORE the 16-site compute, regs->LDS after
// (VMEM latency hidden under ~3k cyc of FMAs), one barrier per window.
// Block 256 thr = 64 batches x {left,right} x 2 lanes; grid 256 = 1/CU.
// Label-site combine fused at the end of the same kernel (both sides of a
// batch live in the same block).

#define NSITES 784
#define DIM    8
#define ODIM   10
#define LABEL  392

__device__ __forceinline__ float dpp_swap(float x) {
    int i = __float_as_int(x);
    // quad_perm [1,0,3,2]: swap adjacent even/odd lanes
    i = __builtin_amdgcn_update_dpp(0, i, 0xB1, 0xF, 0xF, true);
    return __int_as_float(i);
}

__global__ __launch_bounds__(256, 1) void mps_fused(
    const float* __restrict__ x,      // [B, N]
    const float* __restrict__ w0,     // [2, 8]
    const float* __restrict__ Wl,     // [391][d][f][e]
    const float* __restrict__ wlab,   // [8][2][8][10] = 1280
    const float* __restrict__ Wr,     // [390][d][f][e]
    const float* __restrict__ wlast,  // [8][2]
    float* __restrict__ out)          // [B, 10]
{
    __shared__ float wbuf[2][2][16 * 128]; // [buf][side][slot*128 + f*64 + d*8 + e]
    __shared__ float xbl[2][16 * 64];      // [buf][slot*64 + batch]
    __shared__ float xbr[2][16 * 64];
    __shared__ float wlsh[1280];
    __shared__ float vls[64][8];
    __shared__ float rvs[64][8];

    const int tid  = threadIdx.x;
    const int wave = tid >> 6;
    const int lane = tid & 63;
    const int side = wave >> 1;            // 0 = left, 1 = right
    const int f    = lane & 1;             // phi-half owned by this lane
    const int g    = (wave & 1) * 32 + (lane >> 1);  // batch in block 0..63
    const int b0   = blockIdx.x * 64;

    float4 wreg[4];
    float4 xreg[2];

    // ---- staging part A: global -> registers (no LDS, no waits needed yet)
    auto stageA = [&](int cL, int cR) {
        #pragma unroll
        for (int r = 0; r < 4; ++r) {
            const int wcid = tid + 256 * r;            // 0..1023
            const int sw   = wcid >> 9;                // 0 left, 1 right
            const int s    = (wcid >> 5) & 15;         // slot
            const int q5   = wcid & 31;
            const int elem = (q5 >> 2) * 16 + ((q5 >> 1) & 1) * 8 + (q5 & 1) * 4;
            int idx = sw ? (16 * cR + s - 393) : (16 * cL + s - 1);
            const int hi = sw ? 389 : 390;
            idx = idx < 0 ? 0 : (idx > hi ? hi : idx); // clamp; clamped slots unread
            const float* src = (sw ? Wr : Wl) + (size_t)idx * 128 + elem;
            wreg[r] = *(const float4*)src;
        }
        #pragma unroll
        for (int r2 = 0; r2 < 2; ++r2) {
            const int xcid = tid + 256 * r2;           // 0..511
            const int sx   = xcid >> 8;
            const int u    = xcid & 255;
            const int g2   = u >> 2, k = u & 3;
            const int c    = sx ? cR : cL;
            xreg[r2] = *(const float4*)(x + (size_t)(b0 + g2) * NSITES + 16 * c + 4 * k);
        }
    };
    // ---- staging part B: registers -> LDS (runs after the compute block)
    auto stageB = [&](int buf) {
        #pragma unroll
        for (int r = 0; r < 4; ++r) {
            const int wcid = tid + 256 * r;
            const int sw   = wcid >> 9;
            const int s    = (wcid >> 5) & 15;
            const int q5   = wcid & 31;
            const int d    = q5 >> 2, ff = (q5 >> 1) & 1, h = q5 & 1;
            // transpose [d][f][e] -> [f][d][e] (b128-contiguous both sides)
            *(float4*)&wbuf[buf][sw][s * 128 + ff * 64 + d * 8 + 4 * h] = wreg[r];
        }
        #pragma unroll
        for (int r2 = 0; r2 < 2; ++r2) {
            const int xcid = tid + 256 * r2;
            const int sx   = xcid >> 8;
            const int u    = xcid & 255;
            const int g2   = u >> 2, k = u & 3;
            float* xbp = sx ? xbr[buf] : xbl[buf];
            xbp[(4 * k + 0) * 64 + g2] = xreg[r2].x;
            xbp[(4 * k + 1) * 64 + g2] = xreg[r2].y;
            xbp[(4 * k + 2) * 64 + g2] = xreg[r2].z;
            xbp[(4 * k + 3) * 64 + g2] = xreg[r2].w;
        }
    };

    float v[8];

    auto compute_left = [&](int buf, int jlo, int jhi) {
        const float* wp = &wbuf[buf][0][f * 64];
        const float* xp = &xbl[buf][g];
        #pragma unroll
        for (int j = 0; j < 16; ++j) {
            if (j < jlo || j >= jhi) continue;         // folds: jlo/jhi literal
            const float p  = xp[j * 64];
            const float sf = f ? p : 1.0f - p;
            float w[64];
            #pragma unroll
            for (int k = 0; k < 16; ++k)
                *(float4*)&w[k * 4] = *(const float4*)(wp + j * 128 + k * 4);
            float a[8];
            #pragma unroll
            for (int e = 0; e < 8; ++e) a[e] = v[0] * w[e];
            #pragma unroll
            for (int d = 1; d < 8; ++d)
                #pragma unroll
                for (int e = 0; e < 8; ++e) a[e] = fmaf(v[d], w[d * 8 + e], a[e]);
            #pragma unroll
            for (int e = 0; e < 8; ++e) {
                const float t = sf * a[e];
                v[e] = t + dpp_swap(t);
            }
        }
    };
    auto compute_right = [&](int buf, int jlo, int jhi) {   // sites descend
        const float* wp = &wbuf[buf][1][f * 64];
        const float* xp = &xbr[buf][g];
        #pragma unroll
        for (int j2 = 0; j2 < 16; ++j2) {
            const int j = 15 - j2;
            if (j < jlo || j >= jhi) continue;
            const float p  = xp[j * 64];
            const float sf = f ? p : 1.0f - p;
            float w[64];
            #pragma unroll
            for (int k = 0; k < 16; ++k)
                *(float4*)&w[k * 4] = *(const float4*)(wp + j * 128 + k * 4);
            float a[8];
            #pragma unroll
            for (int d = 0; d < 8; ++d) a[d] = v[0] * w[d * 8];
            #pragma unroll
            for (int e = 1; e < 8; ++e)
                #pragma unroll
                for (int d = 0; d < 8; ++d) a[d] = fmaf(v[e], w[d * 8 + e], a[d]);
            #pragma unroll
            for (int d = 0; d < 8; ++d) {
                const float t = sf * a[d];
                v[d] = t + dpp_swap(t);
            }
        }
    };

    // ---- boundary init (both lanes hold full v)
    if (side == 0) {
        const float p0 = x[(size_t)(b0 + g) * NSITES];
        #pragma unroll
        for (int e = 0; e < 8; ++e) v[e] = fmaf(1.0f - p0, w0[e], p0 * w0[8 + e]);
    } else {
        const float pN = x[(size_t)(b0 + g) * NSITES + NSITES - 1];
        #pragma unroll
        for (int d = 0; d < 8; ++d) v[d] = fmaf(1.0f - pN, wlast[2 * d], pN * wlast[2 * d + 1]);
    }

    // ---- prologue: stage window 0 (cL=0, cR=48) + wlab
    stageA(0, 48);
    stageB(0);
    for (int k = tid; k < 320; k += 256)
        *(float4*)&wlsh[k * 4] = *(const float4*)&wlab[k * 4];
    __syncthreads();

    int buf = 0;
    // window 0: left sites 1..15 (j=1..15), right sites 782..768 (j=14..0)
    stageA(1, 47);
    if (side == 0) compute_left(buf, 1, 16); else compute_right(buf, 0, 15);
    stageB(buf ^ 1);
    __syncthreads();
    buf ^= 1;

    #pragma unroll 1
    for (int win = 1; win <= 23; ++win) {
        stageA(win + 1, 47 - win);
        if (side == 0) compute_left(buf, 0, 16); else compute_right(buf, 0, 16);
        stageB(buf ^ 1);
        __syncthreads();
        buf ^= 1;
    }

    // window 24: left sites 384..391 (j=0..7), right sites 399..393 (j=15..9)
    if (side == 0) compute_left(buf, 0, 8); else compute_right(buf, 9, 16);

    // ---- deposit boundary vectors (lanes hold identical v; f==0 writes)
    if (f == 0) {
        float* dst = (side == 0) ? &vls[g][0] : &rvs[g][0];
        *(float4*)&dst[0] = make_float4(v[0], v[1], v[2], v[3]);
        *(float4*)&dst[4] = make_float4(v[4], v[5], v[6], v[7]);
    }
    __syncthreads();

    // ---- fused label-site combine: 64 batches x 10 outputs = 640 items
    #pragma unroll
    for (int rr = 0; rr < 3; ++rr) {
        const int idx = tid + 256 * rr;
        if (idx < 640) {
            const int bi = idx / 10;
            const int o  = idx - bi * 10;
            const float p = x[(size_t)(b0 + bi) * NSITES + LABEL];
            const float q = 1.0f - p;
            float acc = 0.0f;
            #pragma unroll
            for (int d = 0; d < 8; ++d) {
                #pragma unroll
                for (int e = 0; e < 8; ++e) {
                    const float m = fmaf(p, wlsh[(16 * d + 8 + e) * 10 + o],
                                         q * wlsh[(16 * d + e) * 10 + o]);
                    acc = fmaf(vls[bi][d] * rvs[bi][e], m, acc);
                }
            }
            out[(size_t)(b0 + bi) * ODIM + o] = acc;
        }
    }
}

extern "C" void kernel_launch(void* const* d_in, const int* in_sizes, int n_in,
                              void* d_out, int out_size, void* d_ws, size_t ws_size,
                              hipStream_t stream) {
    const float* x     = (const float*)d_in[0];
    const float* w0    = (const float*)d_in[1];
    const float* Wl    = (const float*)d_in[2];
    const float* wlab  = (const float*)d_in[3];
    const float* Wr    = (const float*)d_in[4];
    const float* wlast = (const float*)d_in[5];
    float* out = (float*)d_out;

    mps_fused<<<256, 256, 0, stream>>>(x, w0, Wl, wlab, Wr, wlast, out);
}